// Round 8
// baseline (474.365 us; speedup 1.0000x reference)
//
#include <hip/hip_runtime.h>
#include <math.h>

// Problem: B=128, P=128, D=128, N=4096, fp32 in/out.
// probs = softmax(10*tanh((A@K)/sqrt(128)) + mask) over n.
constexpr int BB = 128;
constexpr int PP = 128;
constexpr int DD = 128;
constexpr int NN = 4096;
constexpr int NF4 = NN / 4;        // 1024 float4 per row
constexpr float kC = 10.0f;
constexpr float k2InvSqrtD = 0.1767766952966369f;   // 2/sqrt(128)

// Empirical laws (R1-R7): 1024-thr blocks cap at 64 VGPRs, ~2x the resident
// waves of 512-thr blocks (which stall at ~24% occupancy = 1 block/CU).
// -> 1024 threads, register footprint designed ~56 < 64.
constexpr int NTHR = 1024;         // 16 waves; each thread owns ONE float4 chunk
constexpr int NWAVES = NTHR / 64;  // 16
constexpr int PT = 8;              // p-rows per block -> acc = 8 float4 = 32 VGPRs
constexpr int DEPTH = 4;           // K ring slots in LDS (16 KB each)

typedef float f32x4 __attribute__((ext_vector_type(4)));

__device__ __forceinline__ float4 ld_nt(const float4* p) {
    f32x4 v = __builtin_nontemporal_load((const f32x4*)p);
    return make_float4(v.x, v.y, v.z, v.w);
}
__device__ __forceinline__ void st_nt(float4* p, float4 s) {
    f32x4 v = {s.x, s.y, s.z, s.w};
    __builtin_nontemporal_store(v, (f32x4*)p);
}

// async global->LDS, 16B/lane: per-lane global addr, wave-uniform LDS base
// (HW scatters to base + lane*16). Tracked by vmcnt.
__device__ __forceinline__ void gload_lds16(const float4* g, float4* l) {
    __builtin_amdgcn_global_load_lds(
        (const __attribute__((address_space(1))) unsigned int*)g,
        (__attribute__((address_space(3))) unsigned int*)l,
        16, 0, 0);
}

__device__ __forceinline__ float4 f4_fma(float a, float4 k, float4 acc) {
    acc.x = fmaf(a, k.x, acc.x);
    acc.y = fmaf(a, k.y, acc.y);
    acc.z = fmaf(a, k.z, acc.z);
    acc.w = fmaf(a, k.w, acc.w);
    return acc;
}

// clipped = 10*tanh(s/sqrt(128)) + m, via tanh(x) = 1 - 2/(e^{2x}+1)
__device__ __forceinline__ float clip1(float s, float m) {
    const float e2 = __expf(s * k2InvSqrtD);
    const float r = __builtin_amdgcn_rcpf(e2 + 1.0f);
    return fmaf(-2.0f * kC, r, kC) + m;
}

__device__ __forceinline__ float4 f4_clip_mask(float4 s, float4 m) {
    float4 r;
    r.x = clip1(s.x, m.x);
    r.y = clip1(s.y, m.y);
    r.z = clip1(s.z, m.z);
    r.w = clip1(s.w, m.w);
    return r;
}

__device__ __forceinline__ float f4_max(float4 s) {
    return fmaxf(fmaxf(s.x, s.y), fmaxf(s.z, s.w));
}

__device__ __forceinline__ float4 f4_expsub(float4 s, float mx) {
    float4 r;
    r.x = __expf(s.x - mx);
    r.y = __expf(s.y - mx);
    r.z = __expf(s.z - mx);
    r.w = __expf(s.w - mx);
    return r;
}

__device__ __forceinline__ float f4_sum(float4 s) {
    return (s.x + s.y) + (s.z + s.w);
}

__device__ __forceinline__ float4 f4_scale(float4 s, float v) {
    s.x *= v; s.y *= v; s.z *= v; s.w *= v;
    return s;
}

// One d-step: 8 wave-uniform A broadcasts into 8 row accumulators (32 v_fma).
__device__ __forceinline__ void fma1(float4 alo, float4 ahi, float4 k,
                                     float4 (&acc)[PT]) {
    acc[0] = f4_fma(alo.x, k, acc[0]);
    acc[1] = f4_fma(alo.y, k, acc[1]);
    acc[2] = f4_fma(alo.z, k, acc[2]);
    acc[3] = f4_fma(alo.w, k, acc[3]);
    acc[4] = f4_fma(ahi.x, k, acc[4]);
    acc[5] = f4_fma(ahi.y, k, acc[5]);
    acc[6] = f4_fma(ahi.z, k, acc[6]);
    acc[7] = f4_fma(ahi.w, k, acc[7]);
}

__global__ __launch_bounds__(NTHR, 1)   // 1024-thr: empirically 64-VGPR cap
void fused_score_softmax(const float* __restrict__ A,   // [B][P][D]
                         const float* __restrict__ K,   // [B][D][N]
                         const float* __restrict__ M,   // [B][P][N]
                         float* __restrict__ O) {       // [B][P][N]
    __shared__ float At[DD][PT];            // A tile transposed (4 KB)
    __shared__ float4 Ks[DEPTH][NF4];       // K ring: 4 x 16 KB = 64 KB
    __shared__ float redmax[PT][NWAVES];
    __shared__ float redsum[PT][NWAVES];

    // XCD-aware swizzle: the 16 p-tiles of one batch land on one XCD, so the
    // batch's K rows are shared through that XCD's L2.
    const int l = blockIdx.x;
    const int xcd = l & 7;
    const int j = l >> 3;                   // 0..255 per XCD
    const int b = xcd + 8 * (j >> 4);       // bijective over [0,128)
    const int p_base = (j & 15) * PT;

    const int tid = (int)threadIdx.x;
    const int lane = tid & 63;
    const int wid = tid >> 6;
    const int wbase = wid * 64;             // wave-uniform LDS base index

    const float4* K4 = (const float4*)(K + (size_t)b * DD * NN);

    // ---- Ring prologue: issue slots 0,1,2 ASAP (their latency hides behind
    // A staging + barrier drain). Wave w stages exactly the float4s its own
    // threads read -> zero barriers in the main loop.
    #pragma unroll
    for (int s = 0; s < DEPTH - 1; ++s)
        gload_lds16(&K4[s * NF4 + tid], &Ks[s][wbase]);

    // ---- Stage A tile (PT x DD) transposed into LDS (1 element/thread) ----
    const float* Ab = A + ((size_t)b * PP + p_base) * DD;
    At[tid & (DD - 1)][tid >> 7] = Ab[tid];
    __syncthreads();

    float4 acc[PT];
    #pragma unroll
    for (int p = 0; p < PT; ++p) acc[p] = make_float4(0.f, 0.f, 0.f, 0.f);

    // ---- Main loop: 1 d-row per phase.
    // Race-free ring discipline (fixes R7's failure):
    //   vmcnt(2)        -> slot d's gload complete (issued = d+3, need 0..d)
    //   ds_read k, A
    //   lgkmcnt(0)      -> ds_read data IS IN REGISTERS
    //   gload(d+3)      -> overwrites slot (d-1)&3; cannot hoist above the
    //                      lgkm asm (memory op), so the previous read is safe.
    #pragma unroll 4
    for (int d = 0; d < DD; ++d) {
        asm volatile("s_waitcnt vmcnt(2)" ::: "memory");
        const int sc = d & (DEPTH - 1);
        const float4 k = Ks[sc][tid];
        const float4 alo = *(const float4*)&At[d][0];   // wave-uniform -> broadcast
        const float4 ahi = *(const float4*)&At[d][4];
        asm volatile("s_waitcnt lgkmcnt(0)" ::: "memory");
        const int dl = (d + 3) & (DD - 1);      // wraps near end (discarded)
        const int sl = (d + 3) & (DEPTH - 1);
        gload_lds16(&K4[dl * NF4 + tid], &Ks[sl][wbase]);
        fma1(alo, ahi, k, acc);
    }

    // ---- Pointwise: clip (10*tanh) + mask; per-row thread-local max ----
    const size_t row_off = ((size_t)b * PP + p_base) * NN;
    const float4* M4 = (const float4*)(M + row_off);
    float4* O4 = (float4*)(O + row_off);

    float mx[PT];
    #pragma unroll
    for (int p = 0; p < PT; ++p) {
        const float4 m = ld_nt(&M4[p * NF4 + tid]);
        acc[p] = f4_clip_mask(acc[p], m);
        mx[p] = f4_max(acc[p]);
    }

    // wave max butterfly
    #pragma unroll
    for (int p = 0; p < PT; ++p) {
        float m = mx[p];
        #pragma unroll
        for (int off = 32; off > 0; off >>= 1)
            m = fmaxf(m, __shfl_xor(m, off));
        if (lane == 0) redmax[p][wid] = m;
    }
    __syncthreads();
    #pragma unroll
    for (int p = 0; p < PT; ++p) {
        const float4 r0 = *(const float4*)&redmax[p][0];
        const float4 r1 = *(const float4*)&redmax[p][4];
        const float4 r2 = *(const float4*)&redmax[p][8];
        const float4 r3 = *(const float4*)&redmax[p][12];
        mx[p] = fmaxf(fmaxf(f4_max(r0), f4_max(r1)),
                      fmaxf(f4_max(r2), f4_max(r3)));
    }

    // ---- exp(s - max); per-row thread-local sum ----
    float sm[PT];
    #pragma unroll
    for (int p = 0; p < PT; ++p) {
        acc[p] = f4_expsub(acc[p], mx[p]);
        sm[p] = f4_sum(acc[p]);
    }
    #pragma unroll
    for (int p = 0; p < PT; ++p) {
        float s = sm[p];
        #pragma unroll
        for (int off = 32; off > 0; off >>= 1)
            s += __shfl_xor(s, off);
        if (lane == 0) redsum[p][wid] = s;
    }
    __syncthreads();

    // ---- normalize and write (nontemporal: output is write-once) ----
    #pragma unroll
    for (int p = 0; p < PT; ++p) {
        const float4 r0 = *(const float4*)&redsum[p][0];
        const float4 r1 = *(const float4*)&redsum[p][4];
        const float4 r2 = *(const float4*)&redsum[p][8];
        const float4 r3 = *(const float4*)&redsum[p][12];
        const float s = (f4_sum(r0) + f4_sum(r1)) + (f4_sum(r2) + f4_sum(r3));
        const float inv = __builtin_amdgcn_rcpf(s);
        st_nt(&O4[p * NF4 + tid], f4_scale(acc[p], inv));
    }
}

extern "C" void kernel_launch(void* const* d_in, const int* in_sizes, int n_in,
                              void* d_out, int out_size, void* d_ws, size_t ws_size,
                              hipStream_t stream) {
    const float* A = (const float*)d_in[0];   // mh_attn_out [128][128][128]
    const float* K = (const float*)d_in[1];   // single_head_key [128][128][4096]
    const float* M = (const float*)d_in[2];   // mask [128][128][4096]
    float* O = (float*)d_out;                 // probs [128][128][4096]

    const int nblocks = BB * (PP / PT);       // 128 * 16 = 2048
    fused_score_softmax<<<dim3(nblocks), dim3(NTHR), 0, stream>>>(A, K, M, O);
}

// Round 9
// 349.082 us; speedup vs baseline: 1.3589x; 1.3589x over previous
//
#include <hip/hip_runtime.h>
#include <math.h>

// Problem: B=128, P=128, D=128, N=4096, fp32 in/out.
// probs = softmax(10*tanh((A@K)/sqrt(128)) + mask) over n.
constexpr int BB = 128;
constexpr int PP = 128;
constexpr int DD = 128;
constexpr int NN = 4096;
constexpr int NF4 = NN / 4;        // 1024 float4 per row
constexpr float kC = 10.0f;
constexpr float k2InvSqrtD = 0.1767766952966369f;   // 2/sqrt(128)

// Empirical laws (R1-R8):
//  - 1024-thr blocks: hard 64-VGPR cap (R3/R8 spill) -> dead end.
//  - All configs run 1 block/CU (512-thr = 2 waves/SIMD).
//  - Cap law fit: 512-thr block (8 waves) schedulable to 256 VGPR;
//    (512,2) -> 128 observed. Betting (512,1) -> 256.
// => R6's proven ring structure, PT doubled to 16, ~195 live regs.
constexpr int NTHR = 512;          // 8 waves
constexpr int NWAVES = NTHR / 64;  // 8
constexpr int PT = 16;             // p-rows per block -> acc = 16x2 f4 = 128 VGPR
constexpr int DEPTH = 4;           // K ring slots in LDS (16 KB each)

typedef float f32x4 __attribute__((ext_vector_type(4)));

__device__ __forceinline__ float4 ld_nt(const float4* p) {
    f32x4 v = __builtin_nontemporal_load((const f32x4*)p);
    return make_float4(v.x, v.y, v.z, v.w);
}
__device__ __forceinline__ void st_nt(float4* p, float4 s) {
    f32x4 v = {s.x, s.y, s.z, s.w};
    __builtin_nontemporal_store(v, (f32x4*)p);
}

// async global->LDS, 16B/lane: per-lane global addr, wave-uniform LDS base
// (HW scatters to base + lane*16). Tracked by vmcnt.
__device__ __forceinline__ void gload_lds16(const float4* g, float4* l) {
    __builtin_amdgcn_global_load_lds(
        (const __attribute__((address_space(1))) unsigned int*)g,
        (__attribute__((address_space(3))) unsigned int*)l,
        16, 0, 0);
}

__device__ __forceinline__ float4 f4_fma(float a, float4 k, float4 acc) {
    acc.x = fmaf(a, k.x, acc.x);
    acc.y = fmaf(a, k.y, acc.y);
    acc.z = fmaf(a, k.z, acc.z);
    acc.w = fmaf(a, k.w, acc.w);
    return acc;
}

// clipped = 10*tanh(s/sqrt(128)) + m, via tanh(x) = 1 - 2/(e^{2x}+1)
__device__ __forceinline__ float clip1(float s, float m) {
    const float e2 = __expf(s * k2InvSqrtD);
    const float r = __builtin_amdgcn_rcpf(e2 + 1.0f);
    return fmaf(-2.0f * kC, r, kC) + m;
}

__device__ __forceinline__ float4 f4_clip_mask(float4 s, float4 m) {
    float4 r;
    r.x = clip1(s.x, m.x);
    r.y = clip1(s.y, m.y);
    r.z = clip1(s.z, m.z);
    r.w = clip1(s.w, m.w);
    return r;
}

__device__ __forceinline__ float f4_max(float4 s) {
    return fmaxf(fmaxf(s.x, s.y), fmaxf(s.z, s.w));
}

__device__ __forceinline__ float4 f4_expsub(float4 s, float mx) {
    float4 r;
    r.x = __expf(s.x - mx);
    r.y = __expf(s.y - mx);
    r.z = __expf(s.z - mx);
    r.w = __expf(s.w - mx);
    return r;
}

__device__ __forceinline__ float f4_sum(float4 s) {
    return (s.x + s.y) + (s.z + s.w);
}

__device__ __forceinline__ float4 f4_scale(float4 s, float v) {
    s.x *= v; s.y *= v; s.z *= v; s.w *= v;
    return s;
}

// One d-step for both n-chunks: 16 wave-uniform A broadcasts, FMA into all 16
// row accumulators (128 v_fma per thread-step).
__device__ __forceinline__ void fma2(float4 a0, float4 a1, float4 a2, float4 a3,
                                     float4 ka, float4 kb,
                                     float4 (&acc0)[PT], float4 (&acc1)[PT]) {
    acc0[0]  = f4_fma(a0.x, ka, acc0[0]);   acc1[0]  = f4_fma(a0.x, kb, acc1[0]);
    acc0[1]  = f4_fma(a0.y, ka, acc0[1]);   acc1[1]  = f4_fma(a0.y, kb, acc1[1]);
    acc0[2]  = f4_fma(a0.z, ka, acc0[2]);   acc1[2]  = f4_fma(a0.z, kb, acc1[2]);
    acc0[3]  = f4_fma(a0.w, ka, acc0[3]);   acc1[3]  = f4_fma(a0.w, kb, acc1[3]);
    acc0[4]  = f4_fma(a1.x, ka, acc0[4]);   acc1[4]  = f4_fma(a1.x, kb, acc1[4]);
    acc0[5]  = f4_fma(a1.y, ka, acc0[5]);   acc1[5]  = f4_fma(a1.y, kb, acc1[5]);
    acc0[6]  = f4_fma(a1.z, ka, acc0[6]);   acc1[6]  = f4_fma(a1.z, kb, acc1[6]);
    acc0[7]  = f4_fma(a1.w, ka, acc0[7]);   acc1[7]  = f4_fma(a1.w, kb, acc1[7]);
    acc0[8]  = f4_fma(a2.x, ka, acc0[8]);   acc1[8]  = f4_fma(a2.x, kb, acc1[8]);
    acc0[9]  = f4_fma(a2.y, ka, acc0[9]);   acc1[9]  = f4_fma(a2.y, kb, acc1[9]);
    acc0[10] = f4_fma(a2.z, ka, acc0[10]);  acc1[10] = f4_fma(a2.z, kb, acc1[10]);
    acc0[11] = f4_fma(a2.w, ka, acc0[11]);  acc1[11] = f4_fma(a2.w, kb, acc1[11]);
    acc0[12] = f4_fma(a3.x, ka, acc0[12]);  acc1[12] = f4_fma(a3.x, kb, acc1[12]);
    acc0[13] = f4_fma(a3.y, ka, acc0[13]);  acc1[13] = f4_fma(a3.y, kb, acc1[13]);
    acc0[14] = f4_fma(a3.z, ka, acc0[14]);  acc1[14] = f4_fma(a3.z, kb, acc1[14]);
    acc0[15] = f4_fma(a3.w, ka, acc0[15]);  acc1[15] = f4_fma(a3.w, kb, acc1[15]);
}

__global__ __launch_bounds__(NTHR, 1)   // bet: cap lifts to 256 VGPR (see law above)
void fused_score_softmax(const float* __restrict__ A,   // [B][P][D]
                         const float* __restrict__ K,   // [B][D][N]
                         const float* __restrict__ M,   // [B][P][N]
                         float* __restrict__ O) {       // [B][P][N]
    __shared__ float At[DD][PT];            // A tile transposed (8 KB)
    __shared__ float4 Ks[DEPTH][NF4];       // K ring: 4 x 16 KB = 64 KB
    __shared__ float redmax[PT][NWAVES];
    __shared__ float redsum[PT][NWAVES];

    // XCD-aware swizzle: the 8 p-tiles of one batch land on one XCD, so the
    // batch's K rows are shared through that XCD's L2.
    const int l = blockIdx.x;
    const int xcd = l & 7;
    const int j = l >> 3;                   // 0..127 per XCD
    const int b = xcd + 8 * (j >> 3);       // bijective over [0,128)
    const int p_base = (j & 7) * PT;

    const int tid = (int)threadIdx.x;
    const int lane = tid & 63;
    const int wid = tid >> 6;
    const int wbase = wid * 64;             // wave-uniform LDS base index

    const float4* K4 = (const float4*)(K + (size_t)b * DD * NN);

    // ---- Ring prologue: issue slots 0,1,2 (2 loads each; 6 outstanding).
    // Wave w stages exactly the float4s its own threads read -> zero barriers
    // in the main loop; ordering is per-wave via counted vmcnt.
    #pragma unroll
    for (int s = 0; s < DEPTH - 1; ++s) {
        gload_lds16(&K4[s * NF4 + tid],       &Ks[s][wbase]);
        gload_lds16(&K4[s * NF4 + 512 + tid], &Ks[s][512 + wbase]);
    }

    // ---- Stage A tile (PT x DD) transposed into LDS (4 elements/thread) ----
    const float* Ab = A + ((size_t)b * PP + p_base) * DD;
    #pragma unroll
    for (int i = 0; i < 4; ++i) {
        const int e = tid + i * NTHR;
        At[e & (DD - 1)][e >> 7] = Ab[e];
    }
    __syncthreads();

    float4 acc0[PT], acc1[PT];
    #pragma unroll
    for (int p = 0; p < PT; ++p) {
        acc0[p] = make_float4(0.f, 0.f, 0.f, 0.f);
        acc1[p] = make_float4(0.f, 0.f, 0.f, 0.f);
    }

    asm volatile("s_waitcnt vmcnt(4)" ::: "memory");   // slot 0 landed
    float4 kXa = Ks[0][tid], kXb = Ks[0][512 + tid];
    float4 aX0 = *(const float4*)&At[0][0];
    float4 aX1 = *(const float4*)&At[0][4];
    float4 aX2 = *(const float4*)&At[0][8];
    float4 aX3 = *(const float4*)&At[0][12];

    // Race-free ring discipline (R6-proven): slot t+1 is ds_read in phase 1 of
    // iter t; its overwrite (gload for d=t+5) is issued in iter t+2, after the
    // compiler's lgkm wait for phase 2's FMAs -> a full iteration of slack.
    #pragma unroll 2
    for (int t = 0; t < DD; t += 2) {
        // phase 1: prefetch Y (d=t+1) ds_reads, issue loads for d=t+3, FMA X.
        asm volatile("s_waitcnt vmcnt(2)" ::: "memory");
        const int s1 = (t + 1) & (DEPTH - 1);
        float4 kYa = Ks[s1][tid], kYb = Ks[s1][512 + tid];
        float4 aY0 = *(const float4*)&At[t + 1][0];
        float4 aY1 = *(const float4*)&At[t + 1][4];
        float4 aY2 = *(const float4*)&At[t + 1][8];
        float4 aY3 = *(const float4*)&At[t + 1][12];
        {
            const int dl = (t + 3) & (DD - 1);      // wraps near end (discarded)
            const int sl = (t + 3) & (DEPTH - 1);
            gload_lds16(&K4[dl * NF4 + tid],       &Ks[sl][wbase]);
            gload_lds16(&K4[dl * NF4 + 512 + tid], &Ks[sl][512 + wbase]);
        }
        fma2(aX0, aX1, aX2, aX3, kXa, kXb, acc0, acc1);

        // phase 2: prefetch X (d=t+2), issue loads for d=t+4, FMA Y.
        asm volatile("s_waitcnt vmcnt(2)" ::: "memory");
        const int s2 = (t + 2) & (DEPTH - 1);
        kXa = Ks[s2][tid]; kXb = Ks[s2][512 + tid];
        const int dn = (t + 2) & (DD - 1);
        aX0 = *(const float4*)&At[dn][0];
        aX1 = *(const float4*)&At[dn][4];
        aX2 = *(const float4*)&At[dn][8];
        aX3 = *(const float4*)&At[dn][12];
        {
            const int dl = (t + 4) & (DD - 1);
            const int sl = (t + 4) & (DEPTH - 1);
            gload_lds16(&K4[dl * NF4 + tid],       &Ks[sl][wbase]);
            gload_lds16(&K4[dl * NF4 + 512 + tid], &Ks[sl][512 + wbase]);
        }
        fma2(aY0, aY1, aY2, aY3, kYa, kYb, acc0, acc1);
    }

    // ---- Pointwise: clip (10*tanh) + mask; per-row thread-local max ----
    const size_t row_off = ((size_t)b * PP + p_base) * NN;
    const float4* M4 = (const float4*)(M + row_off);
    float4* O4 = (float4*)(O + row_off);

    float mx[PT];
    #pragma unroll
    for (int p = 0; p < PT; ++p) {
        const float4 m0 = ld_nt(&M4[p * NF4 + tid]);
        const float4 m1 = ld_nt(&M4[p * NF4 + NTHR + tid]);
        acc0[p] = f4_clip_mask(acc0[p], m0);
        acc1[p] = f4_clip_mask(acc1[p], m1);
        mx[p] = fmaxf(f4_max(acc0[p]), f4_max(acc1[p]));
    }

    // wave max butterfly
    #pragma unroll
    for (int p = 0; p < PT; ++p) {
        float m = mx[p];
        #pragma unroll
        for (int off = 32; off > 0; off >>= 1)
            m = fmaxf(m, __shfl_xor(m, off));
        if (lane == 0) redmax[p][wid] = m;
    }
    __syncthreads();
    #pragma unroll
    for (int p = 0; p < PT; ++p) {
        const float4 r0 = *(const float4*)&redmax[p][0];
        const float4 r1 = *(const float4*)&redmax[p][4];
        mx[p] = fmaxf(f4_max(r0), f4_max(r1));
    }

    // ---- exp(s - max); per-row thread-local sum ----
    float sm[PT];
    #pragma unroll
    for (int p = 0; p < PT; ++p) {
        acc0[p] = f4_expsub(acc0[p], mx[p]);
        acc1[p] = f4_expsub(acc1[p], mx[p]);
        sm[p] = f4_sum(acc0[p]) + f4_sum(acc1[p]);
    }
    #pragma unroll
    for (int p = 0; p < PT; ++p) {
        float s = sm[p];
        #pragma unroll
        for (int off = 32; off > 0; off >>= 1)
            s += __shfl_xor(s, off);
        if (lane == 0) redsum[p][wid] = s;
    }
    __syncthreads();

    // ---- normalize and write (nontemporal: output is write-once) ----
    #pragma unroll
    for (int p = 0; p < PT; ++p) {
        const float4 r0 = *(const float4*)&redsum[p][0];
        const float4 r1 = *(const float4*)&redsum[p][4];
        const float s = f4_sum(r0) + f4_sum(r1);
        const float inv = __builtin_amdgcn_rcpf(s);
        st_nt(&O4[p * NF4 + tid], f4_scale(acc0[p], inv));
        st_nt(&O4[p * NF4 + NTHR + tid], f4_scale(acc1[p], inv));
    }
}

extern "C" void kernel_launch(void* const* d_in, const int* in_sizes, int n_in,
                              void* d_out, int out_size, void* d_ws, size_t ws_size,
                              hipStream_t stream) {
    const float* A = (const float*)d_in[0];   // mh_attn_out [128][128][128]
    const float* K = (const float*)d_in[1];   // single_head_key [128][128][4096]
    const float* M = (const float*)d_in[2];   // mask [128][128][4096]
    float* O = (float*)d_out;                 // probs [128][128][4096]

    const int nblocks = BB * (PP / PT);       // 128 * 8 = 1024
    fused_score_softmax<<<dim3(nblocks), dim3(NTHR), 0, stream>>>(A, K, M, O);
}